// Round 13
// baseline (282.766 us; speedup 1.0000x reference)
//
#include <hip/hip_runtime.h>

// (B, N, D, H) = (8, 4096, 256, 8), PS=8 -> image 64x64; blocked m=fine pos, n=tile idx.
// SPEC FACT 1: no softmax temperature; logit sigma ~16. f16 inputs + fp32 MFMA acc -> logit err ~0.01 (safe).
// SPEC FACT 2: Z = einsum('bhmnd,hdv->bmnd', O, o) is DIAGONAL in d, SUMS v:
//   Z[...,d] = sum_h O_h[...,d] * os[h][d], os[h][d] = sum_v o[h,d,v].
// SPEC FACT 3: S[m][z] = sum_d' W[m][d'] A_g[z][d'], W = A_g M_h, M_h = q_h k^T.
// FUSION (r13): ln1 was a pure pass-through (read x 32MB -> write aH 16MB -> attn re-reads 16MB).
//   LN1 now computed INSIDE attn's staging (identical wave-butterfly order -> bitwise-identical
//   shA bits); aH deleted; osum+prepM+prepT merged into ONE 1288-block dispatch (removes 2
//   full-drain boundaries where the GPU sat ~idle). Dispatches: 6 -> 3.
// ACCOUNTING (r11/r12): attn=122.4; hidden remainder 154.5 across {prep*, ln1, mlp}, all <=63 us
//   (r11 split proof). Dispatch-boundary tax measured ~4.5 us (r10->r11).
// SPILL LESSON (r7): fat register prefetch -> ~250 arch regs -> 250 MB scratch traffic. Attn
//   streams Mt inline. Staging xr[16] is transient (~180 peak, under 256). Watch FETCH_SIZE.
// OCCUPANCY LESSON (r6): 512-thread blocks cap at 1 block/CU; 256-thread blocks give 2+ barrier
//   domains per CU. REGISTER LESSON (r3): launch_bounds waves/EU too high -> VGPR clamp -> spill
//   (unified VGPR+AGPR file: 4 waves/EU budget = 128 TOTAL regs incl. accumulators).
// MFMA conventions (verified r6/r7, absmax 0.125): mfma_f32_16x16x32_f16 computes C = A @ B^T:
//   A-frag: A[m = l16][k = quad*8 + j]; B-frag same over n-rows; C/D: col = l16, row = quad*4 + reg.
// Z kept in BLOCKED layout, TWO buffers (mode0 heads 0-3, mode1 heads 4-7); mlp sums them in fp32.
#define Bc   8
#define Tc   4096
#define Dc   256
#define EPSc 1e-5f

typedef _Float16 half_t;
typedef __attribute__((ext_vector_type(4))) _Float16 half4_t;
typedef __attribute__((ext_vector_type(8))) _Float16 frag8;
typedef __attribute__((ext_vector_type(4))) float f32x4;

#define MFMA_F16(a, b, c) __builtin_amdgcn_mfma_f32_16x16x32_f16((a), (b), (c), 0, 0, 0)

// ---------------- merged prep: [0,512) prepM | [512,1280) prepT | [1280,1288) osum ----------------
// prepM: Mt[h][e][d] = M_h[d][e] = sum_i q[h][d][i]*k[e][i]  (f16), 32x32 tile per block.
// prepT: transpose v/w1/w2 -> f16 [n][d].  osum: os[h][d] = sum_v o[h,d,v].
__global__ __launch_bounds__(256) void prep_kernel(
    const float* __restrict__ q, const float* __restrict__ k,
    const float* __restrict__ v, const float* __restrict__ w1, const float* __restrict__ w2,
    const float* __restrict__ o,
    half_t* __restrict__ Mt, half_t* vt, half_t* w1t, half_t* w2t, float* __restrict__ os) {
  __shared__ float shK[32 * 260];   // 32.5 KB (prepM only)
  __shared__ float shQ[32 * 260];   // 32.5 KB
  int bid = blockIdx.x, tid = threadIdx.x;
  if (bid < 512) {
    int h = bid >> 6, et = (bid >> 3) & 7, dt = bid & 7;
    const float* kbase = k + (size_t)(et * 32) * 256;
    const float* qbase = q + ((size_t)h * 256 + dt * 32) * 256;
    #pragma unroll
    for (int r = 0; r < 8; r++) {
      int f = r * 256 + tid;
      int row = f >> 6, c4 = (f & 63) * 4;
      *(float4*)&shK[row * 260 + c4] = *(const float4*)&kbase[(size_t)row * 256 + c4];
      *(float4*)&shQ[row * 260 + c4] = *(const float4*)&qbase[(size_t)row * 256 + c4];
    }
    __syncthreads();
    int e = tid & 31, dg = tid >> 5;
    const float* kr = &shK[e * 260];
    const float* q0 = &shQ[(dg * 4 + 0) * 260];
    const float* q1 = &shQ[(dg * 4 + 1) * 260];
    const float* q2 = &shQ[(dg * 4 + 2) * 260];
    const float* q3 = &shQ[(dg * 4 + 3) * 260];
    float a0 = 0.f, a1 = 0.f, a2 = 0.f, a3 = 0.f;
    #pragma unroll 4
    for (int kk = 0; kk < 256; kk += 4) {
      float4 kv = *(const float4*)&kr[kk];
      float4 v0 = *(const float4*)&q0[kk];
      float4 v1 = *(const float4*)&q1[kk];
      float4 v2 = *(const float4*)&q2[kk];
      float4 v3 = *(const float4*)&q3[kk];
      a0 += v0.x * kv.x + v0.y * kv.y + v0.z * kv.z + v0.w * kv.w;
      a1 += v1.x * kv.x + v1.y * kv.y + v1.z * kv.z + v1.w * kv.w;
      a2 += v2.x * kv.x + v2.y * kv.y + v2.z * kv.z + v2.w * kv.w;
      a3 += v3.x * kv.x + v3.y * kv.y + v3.z * kv.z + v3.w * kv.w;
    }
    half4_t outv;
    outv[0] = (half_t)a0; outv[1] = (half_t)a1; outv[2] = (half_t)a2; outv[3] = (half_t)a3;
    *(half4_t*)&Mt[((size_t)h * 256 + et * 32 + e) * 256 + dt * 32 + dg * 4] = outv;
  } else if (bid < 1280) {
    int b2 = bid - 512;
    int which = b2 >> 8, n = b2 & 255, d = tid;
    const float* src = which == 0 ? v : (which == 1 ? w1 : w2);
    half_t* dst = which == 0 ? vt : (which == 1 ? w1t : w2t);
    dst[(size_t)n * 256 + d] = (half_t)src[(size_t)d * 256 + n];
  } else {
    int h = bid - 1280, d = tid;
    const float* row = o + ((size_t)h * 256 + d) * 256;
    float s = 0.f;
    #pragma unroll 8
    for (int vv = 0; vv < 256; vv += 4) {
      float4 r4 = *(const float4*)&row[vv];
      s += r4.x + r4.y + r4.z + r4.w;
    }
    os[h * 256 + d] = s;
  }
}

// ---------------- fully fused attention: LN1 + W + score + softmax + PV, 4 heads per block ----------------
// One 256-thread block (4 waves) per (mode, b, slice). LDS 75 KB -> 2 blocks/CU.
// Staging reads x directly and applies LN1 in-wave (identical math/order to the old ln1_kernel ->
// bitwise-identical shA). NO register prefetch of Mt (r7 spill lesson): stream loads inline.
__global__ __launch_bounds__(256, 2) void attn_kernel(
    const float* __restrict__ x, const float* __restrict__ lw, const float* __restrict__ lb,
    const half_t* __restrict__ Mt, const half_t* __restrict__ vt, const float* __restrict__ osum,
    half_t* __restrict__ Z0, half_t* __restrict__ Z1) {
  __shared__ half_t shA[64 * 264];               // A_g[z][d], 33.0 KB
  __shared__ half_t shU[64 * 264 + 64 * 72];     // union: shVT(256x72=36KB) | shW(33KB)+shP(9KB)
  half_t* shVT = shU;
  half_t* shW  = shU;
  half_t* shP  = shU + 64 * 264;
  int tid = threadIdx.x, lane = tid & 63, w = tid >> 6;   // w in 0..3
  int l16 = lane & 15, quad = lane >> 4;
  int g = blockIdx.x;
  int mode = g >> 9, gg = g & 511, b = gg >> 6, slice = gg & 63;
  int hbase = mode * 4;
  half_t* Z = mode ? Z1 : Z0;

  // --- stage A_g with FUSED LN1: wave w owns rows z = w*16 + i; row = coalesced 1KB x read ---
  {
    float4 wv4 = *(const float4*)&lw[lane * 4];
    float4 bv4 = *(const float4*)&lb[lane * 4];
    float4 xr[16];
    #pragma unroll
    for (int i = 0; i < 16; i++) {
      int z = w * 16 + i;
      int m = mode ? slice : z, n = mode ? z : slice;
      int hh = ((n >> 3) << 3) + (m >> 3), ww2 = ((n & 7) << 3) + (m & 7);
      int trow = b * 4096 + hh * 64 + ww2;
      xr[i] = *(const float4*)&x[(size_t)trow * 256 + lane * 4];
    }
    #pragma unroll
    for (int i = 0; i < 16; i++) {
      int z = w * 16 + i;
      float4 vv = xr[i];
      float s  = vv.x + vv.y + vv.z + vv.w;
      float sq = vv.x * vv.x + vv.y * vv.y + vv.z * vv.z + vv.w * vv.w;
      #pragma unroll
      for (int off = 1; off < 64; off <<= 1) { s += __shfl_xor(s, off); sq += __shfl_xor(sq, off); }
      float mean = s * (1.f / 256), var = sq * (1.f / 256) - mean * mean;
      float r = rsqrtf(var + EPSc);
      half4_t y;
      y[0] = (half_t)((vv.x - mean) * r * wv4.x + bv4.x);
      y[1] = (half_t)((vv.y - mean) * r * wv4.y + bv4.y);
      y[2] = (half_t)((vv.z - mean) * r * wv4.z + bv4.z);
      y[3] = (half_t)((vv.w - mean) * r * wv4.w + bv4.w);
      *(half4_t*)&shA[z * 264 + lane * 4] = y;
    }
  }
  __syncthreads();

  // --- vtrans: VT_g[vout][z] = sum_d v[d][vout] A_g[z][d]; wave owns vout [w*64,+64), 2 halves ---
  #pragma unroll
  for (int dth = 0; dth < 2; dth++) {
    f32x4 vacc[2][4];
    #pragma unroll
    for (int dt2 = 0; dt2 < 2; dt2++)
      #pragma unroll
      for (int zt = 0; zt < 4; zt++) vacc[dt2][zt] = (f32x4){0.f, 0.f, 0.f, 0.f};
    #pragma unroll
    for (int ks = 0; ks < 8; ks++) {
      int k0 = ks * 32 + quad * 8;
      frag8 vf0 = *(const frag8*)&vt[(size_t)(w * 64 + dth * 32 +  0 + l16) * 256 + k0];
      frag8 vf1 = *(const frag8*)&vt[(size_t)(w * 64 + dth * 32 + 16 + l16) * 256 + k0];
      frag8 bfr[4];
      #pragma unroll
      for (int zt = 0; zt < 4; zt++)
        bfr[zt] = *(const frag8*)&shA[(zt * 16 + l16) * 264 + k0];
      #pragma unroll
      for (int zt = 0; zt < 4; zt++) {
        vacc[0][zt] = MFMA_F16(vf0, bfr[zt], vacc[0][zt]);
        vacc[1][zt] = MFMA_F16(vf1, bfr[zt], vacc[1][zt]);
      }
    }
    #pragma unroll
    for (int dt2 = 0; dt2 < 2; dt2++)
      #pragma unroll
      for (int zt = 0; zt < 4; zt++)
        #pragma unroll
        for (int r = 0; r < 4; r++)
          shVT[(w * 64 + dth * 32 + dt2 * 16 + quad * 4 + r) * 72 + zt * 16 + l16] = (half_t)vacc[dt2][zt][r];
  }
  __syncthreads();

  // --- register-cache this wave's VT fragments (rows w*64+dt*16+l16, both k-halves) ---
  frag8 vtreg[4][2];
  #pragma unroll
  for (int dt = 0; dt < 4; dt++)
    #pragma unroll
    for (int ks = 0; ks < 2; ks++)
      vtreg[dt][ks] = *(const frag8*)&shVT[(w * 64 + dt * 16 + l16) * 72 + ks * 32 + quad * 8];

  float osv[4][4];
  #pragma unroll
  for (int hh = 0; hh < 4; hh++)
    #pragma unroll
    for (int dt = 0; dt < 4; dt++)
      osv[hh][dt] = osum[(hbase + hh) * 256 + w * 64 + dt * 16 + l16];

  f32x4 zacc[4][4];   // fp32 Z accumulator: [m-frag][d-sub], d = w*64 + dt*16 + l16
  #pragma unroll
  for (int mf = 0; mf < 4; mf++)
    #pragma unroll
    for (int dt = 0; dt < 4; dt++) zacc[mf][dt] = (f32x4){0.f, 0.f, 0.f, 0.f};
  __syncthreads();   // vtreg loaded; shU free for shW overlay

  #pragma unroll
  for (int hh = 0; hh < 4; hh++) {
    const half_t* Mth = Mt + (size_t)(hbase + hh) * 65536;
    // --- W-phase: two e-halves of 32 cols each; Mt streamed inline (no reg prefetch) ---
    #pragma unroll
    for (int eh = 0; eh < 2; eh++) {
      f32x4 wacc[2][4];
      #pragma unroll
      for (int et2 = 0; et2 < 2; et2++)
        #pragma unroll
        for (int mf = 0; mf < 4; mf++) wacc[et2][mf] = (f32x4){0.f, 0.f, 0.f, 0.f};
      #pragma unroll
      for (int ks = 0; ks < 8; ks++) {
        int k0 = ks * 32 + quad * 8;
        frag8 bf0 = *(const frag8*)&Mth[(size_t)(w * 64 + eh * 32 +  0 + l16) * 256 + k0];
        frag8 bf1 = *(const frag8*)&Mth[(size_t)(w * 64 + eh * 32 + 16 + l16) * 256 + k0];
        frag8 af[4];
        #pragma unroll
        for (int mf = 0; mf < 4; mf++) af[mf] = *(const frag8*)&shA[(mf * 16 + l16) * 264 + k0];
        #pragma unroll
        for (int mf = 0; mf < 4; mf++) {
          wacc[0][mf] = MFMA_F16(af[mf], bf0, wacc[0][mf]);
          wacc[1][mf] = MFMA_F16(af[mf], bf1, wacc[1][mf]);
        }
      }
      #pragma unroll
      for (int et2 = 0; et2 < 2; et2++)
        #pragma unroll
        for (int mf = 0; mf < 4; mf++)
          #pragma unroll
          for (int r = 0; r < 4; r++)
            shW[(mf * 16 + quad * 4 + r) * 264 + w * 64 + eh * 32 + et2 * 16 + l16] = (half_t)wacc[et2][mf][r];
    }
    __syncthreads();
    // --- S = W @ A_g^T + softmax; ALL 4 waves, wave = m-quarter (m = w*16 + l16) ---
    {
      f32x4 sacc[4];
      #pragma unroll
      for (int zt = 0; zt < 4; zt++) sacc[zt] = (f32x4){0.f, 0.f, 0.f, 0.f};
      #pragma unroll
      for (int ks = 0; ks < 8; ks++) {
        int k0 = ks * 32 + quad * 8;
        frag8 wf = *(const frag8*)&shW[(w * 16 + l16) * 264 + k0];
        #pragma unroll
        for (int zt = 0; zt < 4; zt++) {
          frag8 kf = *(const frag8*)&shA[(zt * 16 + l16) * 264 + k0];
          sacc[zt] = MFMA_F16(wf, kf, sacc[zt]);
        }
      }
      #pragma unroll
      for (int r = 0; r < 4; r++) {
        float mx = fmaxf(fmaxf(sacc[0][r], sacc[1][r]), fmaxf(sacc[2][r], sacc[3][r]));
        #pragma unroll
        for (int off = 1; off < 16; off <<= 1) mx = fmaxf(mx, __shfl_xor(mx, off));
        float e0 = __expf(sacc[0][r] - mx), e1 = __expf(sacc[1][r] - mx);
        float e2 = __expf(sacc[2][r] - mx), e3 = __expf(sacc[3][r] - mx);
        float sum = e0 + e1 + e2 + e3;
        #pragma unroll
        for (int off = 1; off < 16; off <<= 1) sum += __shfl_xor(sum, off);
        float inv = 1.f / sum;
        int m = w * 16 + quad * 4 + r;
        shP[m * 72 + l16 +  0] = (half_t)(e0 * inv);
        shP[m * 72 + l16 + 16] = (half_t)(e1 * inv);
        shP[m * 72 + l16 + 32] = (half_t)(e2 * inv);
        shP[m * 72 + l16 + 48] = (half_t)(e3 * inv);
      }
    }
    __syncthreads();
    // --- PV: O[m][vout] = P @ VT^T (VT in registers); zacc += O * os[h] ---
    #pragma unroll
    for (int mf = 0; mf < 4; mf++) {
      frag8 pf0 = *(const frag8*)&shP[(mf * 16 + l16) * 72 +  0 + quad * 8];
      frag8 pf1 = *(const frag8*)&shP[(mf * 16 + l16) * 72 + 32 + quad * 8];
      #pragma unroll
      for (int dt = 0; dt < 4; dt++) {
        f32x4 oacc = (f32x4){0.f, 0.f, 0.f, 0.f};
        oacc = MFMA_F16(pf0, vtreg[dt][0], oacc);
        oacc = MFMA_F16(pf1, vtreg[dt][1], oacc);
        #pragma unroll
        for (int r = 0; r < 4; r++) zacc[mf][dt][r] += oacc[r] * osv[hh][dt];
      }
    }
  }

  // --- Z writeback: stage f16 into shA (dead after last S-phase), coalesced 16B stores ---
  #pragma unroll
  for (int mf = 0; mf < 4; mf++)
    #pragma unroll
    for (int dt = 0; dt < 4; dt++)
      #pragma unroll
      for (int r = 0; r < 4; r++)
        shA[(mf * 16 + quad * 4 + r) * 264 + w * 64 + dt * 16 + l16] = (half_t)zacc[mf][dt][r];
  __syncthreads();
  #pragma unroll
  for (int i = 0; i < 8; i++) {
    int slot = i * 256 + tid;
    int grow = slot >> 5, c8 = (slot & 31) * 8;
    size_t zrow = mode ? ((size_t)(b * 64 + slice) * 64 + grow) : ((size_t)(b * 64 + grow) * 64 + slice);
    *(frag8*)&Z[zrow * 256 + c8] = *(const frag8*)&shA[grow * 264 + c8];
  }
}

// ---------------- fused tail: resid + LN2 + fc1(relu) + fc2(+resid) -> out ----------------
// One 256-thread block per 64 token rows (grid 512 = ONE resident round at 2 blocks/CU).
// LDS 66 KB (shH + shHH). Epilogue RECOMPUTES v = x+Z0+Z1 (same fp32 order; bitwise-identical).
__global__ __launch_bounds__(256, 2) void mlp_kernel(
    const float* __restrict__ x, const half_t* __restrict__ Z0, const half_t* __restrict__ Z1,
    const float* __restrict__ lw, const float* __restrict__ lb,
    const half_t* __restrict__ w1t, const float* __restrict__ b1,
    const half_t* __restrict__ w2t, const float* __restrict__ b2,
    float* __restrict__ out) {
  __shared__ half_t shH[64 * 264];   // LN output h (f16), 33 KB
  __shared__ half_t shHH[64 * 264];  // fc1 output H (f16), 33 KB
  int tid = threadIdx.x, lane = tid & 63, w = tid >> 6;
  int l16 = lane & 15, quad = lane >> 4;
  int row0 = blockIdx.x * 64;

  // --- per-row: v = x + Z0 + Z1 (Z via inverse blocked permute); LN -> h (16 rows per wave) ---
  #pragma unroll 4
  for (int i = 0; i < 16; i++) {
    int rl = w * 16 + i;
    int row = row0 + rl;
    size_t base = (size_t)row * 256 + lane * 4;
    int bb = row >> 12, p = row & 4095, hh = p >> 6, ww = p & 63;
    int m = (hh & 7) * 8 + (ww & 7), n = (hh >> 3) * 8 + (ww >> 3);
    size_t zbase = ((size_t)((bb * 64 + m) * 64 + n)) * 256 + lane * 4;
    float4 xv = *(const float4*)&x[base];
    half4_t zv0 = *(const half4_t*)&Z0[zbase];
    half4_t zv1 = *(const half4_t*)&Z1[zbase];
    float4 v;
    v.x = xv.x + (float)zv0[0] + (float)zv1[0];
    v.y = xv.y + (float)zv0[1] + (float)zv1[1];
    v.z = xv.z + (float)zv0[2] + (float)zv1[2];
    v.w = xv.w + (float)zv0[3] + (float)zv1[3];
    float s  = v.x + v.y + v.z + v.w;
    float sq = v.x * v.x + v.y * v.y + v.z * v.z + v.w * v.w;
    #pragma unroll
    for (int off = 1; off < 64; off <<= 1) { s += __shfl_xor(s, off); sq += __shfl_xor(sq, off); }
    float mean = s * (1.f / 256), var = sq * (1.f / 256) - mean * mean;
    float r = rsqrtf(var + EPSc);
    float4 wv = *(const float4*)&lw[lane * 4];
    float4 bv = *(const float4*)&lb[lane * 4];
    half4_t y;
    y[0] = (half_t)((v.x - mean) * r * wv.x + bv.x);
    y[1] = (half_t)((v.y - mean) * r * wv.y + bv.y);
    y[2] = (half_t)((v.z - mean) * r * wv.z + bv.z);
    y[3] = (half_t)((v.w - mean) * r * wv.w + bv.w);
    *(half4_t*)&shH[rl * 264 + lane * 4] = y;
  }
  __syncthreads();

  // --- fc1: H = relu(h @ W1 + b1); wave w owns cols [w*64, +64), 4 m-frags (64 rows) ---
  {
    f32x4 acc[4][4];
    #pragma unroll
    for (int mf = 0; mf < 4; mf++)
      #pragma unroll
      for (int nt = 0; nt < 4; nt++) acc[mf][nt] = (f32x4){0.f, 0.f, 0.f, 0.f};
    #pragma unroll
    for (int ks = 0; ks < 8; ks++) {
      int k0 = ks * 32 + quad * 8;
      frag8 af[4], bf[4];
      #pragma unroll
      for (int mf = 0; mf < 4; mf++) af[mf] = *(const frag8*)&shH[(mf * 16 + l16) * 264 + k0];
      #pragma unroll
      for (int nt = 0; nt < 4; nt++)
        bf[nt] = *(const frag8*)&w1t[(size_t)(w * 64 + nt * 16 + l16) * 256 + k0];
      #pragma unroll
      for (int mf = 0; mf < 4; mf++)
        #pragma unroll
        for (int nt = 0; nt < 4; nt++) acc[mf][nt] = MFMA_F16(af[mf], bf[nt], acc[mf][nt]);
    }
    #pragma unroll
    for (int mf = 0; mf < 4; mf++)
      #pragma unroll
      for (int nt = 0; nt < 4; nt++)
        #pragma unroll
        for (int r = 0; r < 4; r++) {
          int rr = mf * 16 + quad * 4 + r, col = w * 64 + nt * 16 + l16;
          float vv = acc[mf][nt][r] + b1[col];
          vv = fmaxf(vv, 0.f);
          shHH[rr * 264 + col] = (half_t)vv;
        }
  }
  __syncthreads();

  // --- fc2: out = (H @ W2 + b2) + v, v recomputed from x/Z0/Z1 (bitwise-identical order) ---
  {
    f32x4 acc[4][4];
    #pragma unroll
    for (int mf = 0; mf < 4; mf++)
      #pragma unroll
      for (int nt = 0; nt < 4; nt++) acc[mf][nt] = (f32x4){0.f, 0.f, 0.f, 0.f};
    #pragma unroll
    for (int ks = 0; ks < 8; ks++) {
      int k0 = ks * 32 + quad * 8;
      frag8 af[4], bf[4];
      #pragma unroll
      for (int mf = 0; mf < 4; mf++) af[mf] = *(const frag8*)&shHH[(mf * 16 + l16) * 264 + k0];
      #pragma unroll
      for (int nt = 0; nt < 4; nt++)
        bf[nt] = *(const frag8*)&w2t[(size_t)(w * 64 + nt * 16 + l16) * 256 + k0];
      #pragma unroll
      for (int mf = 0; mf < 4; mf++)
        #pragma unroll
        for (int nt = 0; nt < 4; nt++) acc[mf][nt] = MFMA_F16(af[mf], bf[nt], acc[mf][nt]);
    }
    #pragma unroll
    for (int mf = 0; mf < 4; mf++)
      #pragma unroll
      for (int r = 0; r < 4; r++) {
        int rr = mf * 16 + quad * 4 + r;
        int row = row0 + rr;
        int bb = row >> 12, p = row & 4095, hh = p >> 6, ww = p & 63;
        int m = (hh & 7) * 8 + (ww & 7), n = (hh >> 3) * 8 + (ww >> 3);
        size_t zrow = ((size_t)((bb * 64 + m) * 64 + n)) * 256;
        size_t xrow = (size_t)row * 256;
        #pragma unroll
        for (int nt = 0; nt < 4; nt++) {
          int col = w * 64 + nt * 16 + l16;
          float vres = x[xrow + col] + (float)Z0[zrow + col] + (float)Z1[zrow + col];
          float vv = acc[mf][nt][r] + b2[col];
          out[xrow + col] = vv + vres;
        }
      }
  }
}

extern "C" void kernel_launch(void* const* d_in, const int* in_sizes, int n_in,
                              void* d_out, int out_size, void* d_ws, size_t ws_size,
                              hipStream_t stream) {
  (void)in_sizes; (void)n_in; (void)out_size; (void)ws_size;
  const float* x    = (const float*)d_in[0];
  const float* ln1w = (const float*)d_in[1];
  const float* ln1b = (const float*)d_in[2];
  const float* q    = (const float*)d_in[3];
  const float* k    = (const float*)d_in[4];
  const float* v    = (const float*)d_in[5];
  const float* o    = (const float*)d_in[6];
  const float* ln2w = (const float*)d_in[7];
  const float* ln2b = (const float*)d_in[8];
  const float* w1   = (const float*)d_in[9];
  const float* b1   = (const float*)d_in[10];
  const float* w2   = (const float*)d_in[11];
  const float* b2   = (const float*)d_in[12];
  float* out = (float*)d_out;

  const size_t ROWS = (size_t)Bc * Tc;        // 32768
  const size_t ELTS = ROWS * Dc;              // 8,388,608
  const size_t MB16 = ELTS * sizeof(half_t);  // 16 MiB
  char* ws = (char*)d_ws;
  float*  osumB = (float*)ws;
  half_t* Mt    = (half_t*)(ws + (64 << 10));
  half_t* vt    = (half_t*)(ws + (64 << 10) + (1 << 20));
  half_t* w1t   = (half_t*)(ws + (64 << 10) + (1 << 20) + (128 << 10));
  half_t* w2t   = (half_t*)(ws + (64 << 10) + (1 << 20) + (256 << 10));
  half_t* Zb0   = (half_t*)(ws + (2 << 20));
  half_t* Zb1   = (half_t*)(ws + (2 << 20) + MB16);

  // merged prep: prepM (512) | prepT (768) | osum (8)
  prep_kernel <<<1288, 256, 0, stream>>>(q, k, v, w1, w2, o, Mt, vt, w1t, w2t, osumB);
  // fused LN1 + attention: ONE 1024-block dispatch (mode 0 -> Z0, mode 1 -> Z1)
  attn_kernel <<<1024, 256, 0, stream>>>(x, ln1w, ln1b, Mt, vt, osumB, Zb0, Zb1);
  // fused tail: resid + LN2 + fc1 + fc2 + resid -> out (512 x 64-row blocks, one round)
  mlp_kernel  <<<ROWS / 64, 256, 0, stream>>>(x, Zb0, Zb1, ln2w, ln2b, w1t, b1, w2t, b2, out);
}

// Round 14
// 267.427 us; speedup vs baseline: 1.0574x; 1.0574x over previous
//
#include <hip/hip_runtime.h>

// (B, N, D, H) = (8, 4096, 256, 8), PS=8 -> image 64x64; blocked m=fine pos, n=tile idx.
// SPEC FACT 1: no softmax temperature; logit sigma ~16. f16 inputs + fp32 MFMA acc -> logit err ~0.01 (safe).
// SPEC FACT 2: Z = einsum('bhmnd,hdv->bmnd', O, o) is DIAGONAL in d, SUMS v:
//   Z[...,d] = sum_h O_h[...,d] * os[h][d], os[h][d] = sum_v o[h,d,v].
// SPEC FACT 3: S[m][z] = sum_d' W[m][d'] A_g[z][d'], W = A_g M_h, M_h = q_h k^T.
// FUSION LESSON (r13): folding LN1 into attn was a WASH-to-negative: attn 122->139.5 us, FETCH
//   21->38 MB (fp32 x double-read at 4B/elem vs aH 2B; LN butterfly serialized at 8 waves/CU).
//   Bytes moved DOWN but into a low-occupancy kernel -> slower. REVERTED: attn reads aH again;
//   ln1 runs as 512 x 64-row blocks INSIDE the prep dispatch (overlaps prepM/prepT/osum,
//   removes 2 drain boundaries). Dispatches stay 3. ln1 math = original (bitwise-identical aH).
// ACCOUNTING (r11/r12): attn=122; remainder ~155 spread over {prep, ln1, mlp} all <=63 us.
//   Dispatch-boundary tax ~4.5 us (r10->r11).
// SPILL LESSON (r7): fat register prefetch -> ~250 arch regs -> 250 MB scratch traffic. Attn
//   streams Mt inline; 2-block TLP hides latency. Watch FETCH_SIZE for spill regressions.
// OCCUPANCY LESSON (r6): 512-thread blocks cap at 1 block/CU; 256-thread blocks give 2+ barrier
//   domains per CU. REGISTER LESSON (r3): launch_bounds waves/EU too high -> VGPR clamp -> spill
//   (unified VGPR+AGPR file: 4 waves/EU budget = 128 TOTAL regs incl. accumulators).
// MFMA conventions (verified r6/r7, absmax 0.125): mfma_f32_16x16x32_f16 computes C = A @ B^T:
//   A-frag: A[m = l16][k = quad*8 + j]; B-frag same over n-rows; C/D: col = l16, row = quad*4 + reg.
// Z kept in BLOCKED layout, TWO buffers (mode0 heads 0-3, mode1 heads 4-7); mlp sums them in fp32.
#define Bc   8
#define Tc   4096
#define Dc   256
#define EPSc 1e-5f

typedef _Float16 half_t;
typedef __attribute__((ext_vector_type(4))) _Float16 half4_t;
typedef __attribute__((ext_vector_type(8))) _Float16 frag8;
typedef __attribute__((ext_vector_type(4))) float f32x4;

#define MFMA_F16(a, b, c) __builtin_amdgcn_mfma_f32_16x16x32_f16((a), (b), (c), 0, 0, 0)

// ---------------- merged prep: [0,512) prepM | [512,1280) prepT | [1280,1288) osum | [1288,1800) ln1 ----------------
// prepM: Mt[h][e][d] = M_h[d][e] = sum_i q[h][d][i]*k[e][i]  (f16), 32x32 tile per block.
// prepT: transpose v/w1/w2 -> f16 [n][d].  osum: os[h][d] = sum_v o[h,d,v].
// ln1: 64 rows per block (16 x 4-row groups), EXACT original wave-butterfly math -> aH (blocked).
__global__ __launch_bounds__(256) void prep_kernel(
    const float* __restrict__ q, const float* __restrict__ k,
    const float* __restrict__ v, const float* __restrict__ w1, const float* __restrict__ w2,
    const float* __restrict__ o, const float* __restrict__ x,
    const float* __restrict__ lw, const float* __restrict__ lb,
    half_t* __restrict__ Mt, half_t* vt, half_t* w1t, half_t* w2t,
    float* __restrict__ os, half_t* __restrict__ aH) {
  __shared__ float shK[32 * 260];   // 32.5 KB (prepM only)
  __shared__ float shQ[32 * 260];   // 32.5 KB
  int bid = blockIdx.x, tid = threadIdx.x;
  if (bid < 512) {
    int h = bid >> 6, et = (bid >> 3) & 7, dt = bid & 7;
    const float* kbase = k + (size_t)(et * 32) * 256;
    const float* qbase = q + ((size_t)h * 256 + dt * 32) * 256;
    #pragma unroll
    for (int r = 0; r < 8; r++) {
      int f = r * 256 + tid;
      int row = f >> 6, c4 = (f & 63) * 4;
      *(float4*)&shK[row * 260 + c4] = *(const float4*)&kbase[(size_t)row * 256 + c4];
      *(float4*)&shQ[row * 260 + c4] = *(const float4*)&qbase[(size_t)row * 256 + c4];
    }
    __syncthreads();
    int e = tid & 31, dg = tid >> 5;
    const float* kr = &shK[e * 260];
    const float* q0 = &shQ[(dg * 4 + 0) * 260];
    const float* q1 = &shQ[(dg * 4 + 1) * 260];
    const float* q2 = &shQ[(dg * 4 + 2) * 260];
    const float* q3 = &shQ[(dg * 4 + 3) * 260];
    float a0 = 0.f, a1 = 0.f, a2 = 0.f, a3 = 0.f;
    #pragma unroll 4
    for (int kk = 0; kk < 256; kk += 4) {
      float4 kv = *(const float4*)&kr[kk];
      float4 v0 = *(const float4*)&q0[kk];
      float4 v1 = *(const float4*)&q1[kk];
      float4 v2 = *(const float4*)&q2[kk];
      float4 v3 = *(const float4*)&q3[kk];
      a0 += v0.x * kv.x + v0.y * kv.y + v0.z * kv.z + v0.w * kv.w;
      a1 += v1.x * kv.x + v1.y * kv.y + v1.z * kv.z + v1.w * kv.w;
      a2 += v2.x * kv.x + v2.y * kv.y + v2.z * kv.z + v2.w * kv.w;
      a3 += v3.x * kv.x + v3.y * kv.y + v3.z * kv.z + v3.w * kv.w;
    }
    half4_t outv;
    outv[0] = (half_t)a0; outv[1] = (half_t)a1; outv[2] = (half_t)a2; outv[3] = (half_t)a3;
    *(half4_t*)&Mt[((size_t)h * 256 + et * 32 + e) * 256 + dt * 32 + dg * 4] = outv;
  } else if (bid < 1280) {
    int b2 = bid - 512;
    int which = b2 >> 8, n = b2 & 255, d = tid;
    const float* src = which == 0 ? v : (which == 1 ? w1 : w2);
    half_t* dst = which == 0 ? vt : (which == 1 ? w1t : w2t);
    dst[(size_t)n * 256 + d] = (half_t)src[(size_t)d * 256 + n];
  } else if (bid < 1288) {
    int h = bid - 1280, d = tid;
    const float* row = o + ((size_t)h * 256 + d) * 256;
    float s = 0.f;
    #pragma unroll 8
    for (int vv = 0; vv < 256; vv += 4) {
      float4 r4 = *(const float4*)&row[vv];
      s += r4.x + r4.y + r4.z + r4.w;
    }
    os[h * 256 + d] = s;
  } else {
    // ln1: rows [(bid-1288)*64, +64), 4 rows per iteration (one per wave), original math
    int lane = tid & 63;
    int base_row = (bid - 1288) * 64;
    float4 wv = *(const float4*)&lw[lane * 4];
    float4 bv = *(const float4*)&lb[lane * 4];
    #pragma unroll 4
    for (int i = 0; i < 16; i++) {
      int row = base_row + i * 4 + (tid >> 6);
      float4 vv = *(const float4*)&x[(size_t)row * 256 + lane * 4];
      float s  = vv.x + vv.y + vv.z + vv.w;
      float sq = vv.x * vv.x + vv.y * vv.y + vv.z * vv.z + vv.w * vv.w;
      #pragma unroll
      for (int off = 1; off < 64; off <<= 1) { s += __shfl_xor(s, off); sq += __shfl_xor(sq, off); }
      float mean = s * (1.f / 256), var = sq * (1.f / 256) - mean * mean;
      float r = rsqrtf(var + EPSc);
      half4_t y;
      y[0] = (half_t)((vv.x - mean) * r * wv.x + bv.x);
      y[1] = (half_t)((vv.y - mean) * r * wv.y + bv.y);
      y[2] = (half_t)((vv.z - mean) * r * wv.z + bv.z);
      y[3] = (half_t)((vv.w - mean) * r * wv.w + bv.w);
      int bb = row >> 12, p = row & 4095, hh = p >> 6, ww = p & 63;
      int m = (hh & 7) * 8 + (ww & 7), n = (hh >> 3) * 8 + (ww >> 3);
      *(half4_t*)&aH[((size_t)((bb * 64 + m) * 64 + n)) * 256 + lane * 4] = y;
    }
  }
}

// ---------------- fully fused attention: W + score + softmax + PV, 4 heads per block ----------------
// One 256-thread block (4 waves) per (mode, b, slice). LDS 75 KB -> 2 blocks/CU.
// NO register prefetch of Mt (r7 spill lesson): stream loads inline; 2-block TLP hides latency.
__global__ __launch_bounds__(256, 2) void attn_kernel(
    const half_t* __restrict__ aH, const half_t* __restrict__ Mt,
    const half_t* __restrict__ vt, const float* __restrict__ osum,
    half_t* __restrict__ Z0, half_t* __restrict__ Z1) {
  __shared__ half_t shA[64 * 264];               // A_g[z][d], 33.0 KB
  __shared__ half_t shU[64 * 264 + 64 * 72];     // union: shVT(256x72=36KB) | shW(33KB)+shP(9KB)
  half_t* shVT = shU;
  half_t* shW  = shU;
  half_t* shP  = shU + 64 * 264;
  int tid = threadIdx.x, lane = tid & 63, w = tid >> 6;   // w in 0..3
  int l16 = lane & 15, quad = lane >> 4;
  int g = blockIdx.x;
  int mode = g >> 9, gg = g & 511, b = gg >> 6, slice = gg & 63;
  int hbase = mode * 4;
  half_t* Z = mode ? Z1 : Z0;

  // --- stage A_g (64x256 f16 = 32 KB), coalesced: 2048 frag8 slots / 256 threads ---
  #pragma unroll
  for (int i = 0; i < 8; i++) {
    int slot = i * 256 + tid;
    int z = slot >> 5, c8 = (slot & 31) * 8;
    size_t rz = mode ? ((size_t)(b * 64 + slice) * 64 + z) : ((size_t)(b * 64 + z) * 64 + slice);
    *(frag8*)&shA[z * 264 + c8] = *(const frag8*)&aH[rz * 256 + c8];
  }
  __syncthreads();

  // --- vtrans: VT_g[vout][z] = sum_d v[d][vout] A_g[z][d]; wave owns vout [w*64,+64), 2 halves ---
  #pragma unroll
  for (int dth = 0; dth < 2; dth++) {
    f32x4 vacc[2][4];
    #pragma unroll
    for (int dt2 = 0; dt2 < 2; dt2++)
      #pragma unroll
      for (int zt = 0; zt < 4; zt++) vacc[dt2][zt] = (f32x4){0.f, 0.f, 0.f, 0.f};
    #pragma unroll
    for (int ks = 0; ks < 8; ks++) {
      int k0 = ks * 32 + quad * 8;
      frag8 vf0 = *(const frag8*)&vt[(size_t)(w * 64 + dth * 32 +  0 + l16) * 256 + k0];
      frag8 vf1 = *(const frag8*)&vt[(size_t)(w * 64 + dth * 32 + 16 + l16) * 256 + k0];
      frag8 bfr[4];
      #pragma unroll
      for (int zt = 0; zt < 4; zt++)
        bfr[zt] = *(const frag8*)&shA[(zt * 16 + l16) * 264 + k0];
      #pragma unroll
      for (int zt = 0; zt < 4; zt++) {
        vacc[0][zt] = MFMA_F16(vf0, bfr[zt], vacc[0][zt]);
        vacc[1][zt] = MFMA_F16(vf1, bfr[zt], vacc[1][zt]);
      }
    }
    #pragma unroll
    for (int dt2 = 0; dt2 < 2; dt2++)
      #pragma unroll
      for (int zt = 0; zt < 4; zt++)
        #pragma unroll
        for (int r = 0; r < 4; r++)
          shVT[(w * 64 + dth * 32 + dt2 * 16 + quad * 4 + r) * 72 + zt * 16 + l16] = (half_t)vacc[dt2][zt][r];
  }
  __syncthreads();

  // --- register-cache this wave's VT fragments (rows w*64+dt*16+l16, both k-halves) ---
  frag8 vtreg[4][2];
  #pragma unroll
  for (int dt = 0; dt < 4; dt++)
    #pragma unroll
    for (int ks = 0; ks < 2; ks++)
      vtreg[dt][ks] = *(const frag8*)&shVT[(w * 64 + dt * 16 + l16) * 72 + ks * 32 + quad * 8];

  float osv[4][4];
  #pragma unroll
  for (int hh = 0; hh < 4; hh++)
    #pragma unroll
    for (int dt = 0; dt < 4; dt++)
      osv[hh][dt] = osum[(hbase + hh) * 256 + w * 64 + dt * 16 + l16];

  f32x4 zacc[4][4];   // fp32 Z accumulator: [m-frag][d-sub], d = w*64 + dt*16 + l16
  #pragma unroll
  for (int mf = 0; mf < 4; mf++)
    #pragma unroll
    for (int dt = 0; dt < 4; dt++) zacc[mf][dt] = (f32x4){0.f, 0.f, 0.f, 0.f};
  __syncthreads();   // vtreg loaded; shU free for shW overlay

  #pragma unroll
  for (int hh = 0; hh < 4; hh++) {
    const half_t* Mth = Mt + (size_t)(hbase + hh) * 65536;
    // --- W-phase: two e-halves of 32 cols each; Mt streamed inline (no reg prefetch) ---
    #pragma unroll
    for (int eh = 0; eh < 2; eh++) {
      f32x4 wacc[2][4];
      #pragma unroll
      for (int et2 = 0; et2 < 2; et2++)
        #pragma unroll
        for (int mf = 0; mf < 4; mf++) wacc[et2][mf] = (f32x4){0.f, 0.f, 0.f, 0.f};
      #pragma unroll
      for (int ks = 0; ks < 8; ks++) {
        int k0 = ks * 32 + quad * 8;
        frag8 bf0 = *(const frag8*)&Mth[(size_t)(w * 64 + eh * 32 +  0 + l16) * 256 + k0];
        frag8 bf1 = *(const frag8*)&Mth[(size_t)(w * 64 + eh * 32 + 16 + l16) * 256 + k0];
        frag8 af[4];
        #pragma unroll
        for (int mf = 0; mf < 4; mf++) af[mf] = *(const frag8*)&shA[(mf * 16 + l16) * 264 + k0];
        #pragma unroll
        for (int mf = 0; mf < 4; mf++) {
          wacc[0][mf] = MFMA_F16(af[mf], bf0, wacc[0][mf]);
          wacc[1][mf] = MFMA_F16(af[mf], bf1, wacc[1][mf]);
        }
      }
      #pragma unroll
      for (int et2 = 0; et2 < 2; et2++)
        #pragma unroll
        for (int mf = 0; mf < 4; mf++)
          #pragma unroll
          for (int r = 0; r < 4; r++)
            shW[(mf * 16 + quad * 4 + r) * 264 + w * 64 + eh * 32 + et2 * 16 + l16] = (half_t)wacc[et2][mf][r];
    }
    __syncthreads();
    // --- S = W @ A_g^T + softmax; ALL 4 waves, wave = m-quarter (m = w*16 + l16) ---
    {
      f32x4 sacc[4];
      #pragma unroll
      for (int zt = 0; zt < 4; zt++) sacc[zt] = (f32x4){0.f, 0.f, 0.f, 0.f};
      #pragma unroll
      for (int ks = 0; ks < 8; ks++) {
        int k0 = ks * 32 + quad * 8;
        frag8 wf = *(const frag8*)&shW[(w * 16 + l16) * 264 + k0];
        #pragma unroll
        for (int zt = 0; zt < 4; zt++) {
          frag8 kf = *(const frag8*)&shA[(zt * 16 + l16) * 264 + k0];
          sacc[zt] = MFMA_F16(wf, kf, sacc[zt]);
        }
      }
      #pragma unroll
      for (int r = 0; r < 4; r++) {
        float mx = fmaxf(fmaxf(sacc[0][r], sacc[1][r]), fmaxf(sacc[2][r], sacc[3][r]));
        #pragma unroll
        for (int off = 1; off < 16; off <<= 1) mx = fmaxf(mx, __shfl_xor(mx, off));
        float e0 = __expf(sacc[0][r] - mx), e1 = __expf(sacc[1][r] - mx);
        float e2 = __expf(sacc[2][r] - mx), e3 = __expf(sacc[3][r] - mx);
        float sum = e0 + e1 + e2 + e3;
        #pragma unroll
        for (int off = 1; off < 16; off <<= 1) sum += __shfl_xor(sum, off);
        float inv = 1.f / sum;
        int m = w * 16 + quad * 4 + r;
        shP[m * 72 + l16 +  0] = (half_t)(e0 * inv);
        shP[m * 72 + l16 + 16] = (half_t)(e1 * inv);
        shP[m * 72 + l16 + 32] = (half_t)(e2 * inv);
        shP[m * 72 + l16 + 48] = (half_t)(e3 * inv);
      }
    }
    __syncthreads();
    // --- PV: O[m][vout] = P @ VT^T (VT in registers); zacc += O * os[h] ---
    #pragma unroll
    for (int mf = 0; mf < 4; mf++) {
      frag8 pf0 = *(const frag8*)&shP[(mf * 16 + l16) * 72 +  0 + quad * 8];
      frag8 pf1 = *(const frag8*)&shP[(mf * 16 + l16) * 72 + 32 + quad * 8];
      #pragma unroll
      for (int dt = 0; dt < 4; dt++) {
        f32x4 oacc = (f32x4){0.f, 0.f, 0.f, 0.f};
        oacc = MFMA_F16(pf0, vtreg[dt][0], oacc);
        oacc = MFMA_F16(pf1, vtreg[dt][1], oacc);
        #pragma unroll
        for (int r = 0; r < 4; r++) zacc[mf][dt][r] += oacc[r] * osv[hh][dt];
      }
    }
  }

  // --- Z writeback: stage f16 into shA (dead after last S-phase), coalesced 16B stores ---
  #pragma unroll
  for (int mf = 0; mf < 4; mf++)
    #pragma unroll
    for (int dt = 0; dt < 4; dt++)
      #pragma unroll
      for (int r = 0; r < 4; r++)
        shA[(mf * 16 + quad * 4 + r) * 264 + w * 64 + dt * 16 + l16] = (half_t)zacc[mf][dt][r];
  __syncthreads();
  #pragma unroll
  for (int i = 0; i < 8; i++) {
    int slot = i * 256 + tid;
    int grow = slot >> 5, c8 = (slot & 31) * 8;
    size_t zrow = mode ? ((size_t)(b * 64 + slice) * 64 + grow) : ((size_t)(b * 64 + grow) * 64 + slice);
    *(frag8*)&Z[zrow * 256 + c8] = *(const frag8*)&shA[grow * 264 + c8];
  }
}

// ---------------- fused tail: resid + LN2 + fc1(relu) + fc2(+resid) -> out ----------------
// One 256-thread block per 64 token rows (grid 512 = ONE resident round at 2 blocks/CU).
// LDS 66 KB (shH + shHH). Epilogue RECOMPUTES v = x+Z0+Z1 (same fp32 order; bitwise-identical).
__global__ __launch_bounds__(256, 2) void mlp_kernel(
    const float* __restrict__ x, const half_t* __restrict__ Z0, const half_t* __restrict__ Z1,
    const float* __restrict__ lw, const float* __restrict__ lb,
    const half_t* __restrict__ w1t, const float* __restrict__ b1,
    const half_t* __restrict__ w2t, const float* __restrict__ b2,
    float* __restrict__ out) {
  __shared__ half_t shH[64 * 264];   // LN output h (f16), 33 KB
  __shared__ half_t shHH[64 * 264];  // fc1 output H (f16), 33 KB
  int tid = threadIdx.x, lane = tid & 63, w = tid >> 6;
  int l16 = lane & 15, quad = lane >> 4;
  int row0 = blockIdx.x * 64;

  // --- per-row: v = x + Z0 + Z1 (Z via inverse blocked permute); LN -> h (16 rows per wave) ---
  #pragma unroll 4
  for (int i = 0; i < 16; i++) {
    int rl = w * 16 + i;
    int row = row0 + rl;
    size_t base = (size_t)row * 256 + lane * 4;
    int bb = row >> 12, p = row & 4095, hh = p >> 6, ww = p & 63;
    int m = (hh & 7) * 8 + (ww & 7), n = (hh >> 3) * 8 + (ww >> 3);
    size_t zbase = ((size_t)((bb * 64 + m) * 64 + n)) * 256 + lane * 4;
    float4 xv = *(const float4*)&x[base];
    half4_t zv0 = *(const half4_t*)&Z0[zbase];
    half4_t zv1 = *(const half4_t*)&Z1[zbase];
    float4 v;
    v.x = xv.x + (float)zv0[0] + (float)zv1[0];
    v.y = xv.y + (float)zv0[1] + (float)zv1[1];
    v.z = xv.z + (float)zv0[2] + (float)zv1[2];
    v.w = xv.w + (float)zv0[3] + (float)zv1[3];
    float s  = v.x + v.y + v.z + v.w;
    float sq = v.x * v.x + v.y * v.y + v.z * v.z + v.w * v.w;
    #pragma unroll
    for (int off = 1; off < 64; off <<= 1) { s += __shfl_xor(s, off); sq += __shfl_xor(sq, off); }
    float mean = s * (1.f / 256), var = sq * (1.f / 256) - mean * mean;
    float r = rsqrtf(var + EPSc);
    float4 wv = *(const float4*)&lw[lane * 4];
    float4 bv = *(const float4*)&lb[lane * 4];
    half4_t y;
    y[0] = (half_t)((v.x - mean) * r * wv.x + bv.x);
    y[1] = (half_t)((v.y - mean) * r * wv.y + bv.y);
    y[2] = (half_t)((v.z - mean) * r * wv.z + bv.z);
    y[3] = (half_t)((v.w - mean) * r * wv.w + bv.w);
    *(half4_t*)&shH[rl * 264 + lane * 4] = y;
  }
  __syncthreads();

  // --- fc1: H = relu(h @ W1 + b1); wave w owns cols [w*64, +64), 4 m-frags (64 rows) ---
  {
    f32x4 acc[4][4];
    #pragma unroll
    for (int mf = 0; mf < 4; mf++)
      #pragma unroll
      for (int nt = 0; nt < 4; nt++) acc[mf][nt] = (f32x4){0.f, 0.f, 0.f, 0.f};
    #pragma unroll
    for (int ks = 0; ks < 8; ks++) {
      int k0 = ks * 32 + quad * 8;
      frag8 af[4], bf[4];
      #pragma unroll
      for (int mf = 0; mf < 4; mf++) af[mf] = *(const frag8*)&shH[(mf * 16 + l16) * 264 + k0];
      #pragma unroll
      for (int nt = 0; nt < 4; nt++)
        bf[nt] = *(const frag8*)&w1t[(size_t)(w * 64 + nt * 16 + l16) * 256 + k0];
      #pragma unroll
      for (int mf = 0; mf < 4; mf++)
        #pragma unroll
        for (int nt = 0; nt < 4; nt++) acc[mf][nt] = MFMA_F16(af[mf], bf[nt], acc[mf][nt]);
    }
    #pragma unroll
    for (int mf = 0; mf < 4; mf++)
      #pragma unroll
      for (int nt = 0; nt < 4; nt++)
        #pragma unroll
        for (int r = 0; r < 4; r++) {
          int rr = mf * 16 + quad * 4 + r, col = w * 64 + nt * 16 + l16;
          float vv = acc[mf][nt][r] + b1[col];
          vv = fmaxf(vv, 0.f);
          shHH[rr * 264 + col] = (half_t)vv;
        }
  }
  __syncthreads();

  // --- fc2: out = (H @ W2 + b2) + v, v recomputed from x/Z0/Z1 (bitwise-identical order) ---
  {
    f32x4 acc[4][4];
    #pragma unroll
    for (int mf = 0; mf < 4; mf++)
      #pragma unroll
      for (int nt = 0; nt < 4; nt++) acc[mf][nt] = (f32x4){0.f, 0.f, 0.f, 0.f};
    #pragma unroll
    for (int ks = 0; ks < 8; ks++) {
      int k0 = ks * 32 + quad * 8;
      frag8 af[4], bf[4];
      #pragma unroll
      for (int mf = 0; mf < 4; mf++) af[mf] = *(const frag8*)&shHH[(mf * 16 + l16) * 264 + k0];
      #pragma unroll
      for (int nt = 0; nt < 4; nt++)
        bf[nt] = *(const frag8*)&w2t[(size_t)(w * 64 + nt * 16 + l16) * 256 + k0];
      #pragma unroll
      for (int mf = 0; mf < 4; mf++)
        #pragma unroll
        for (int nt = 0; nt < 4; nt++) acc[mf][nt] = MFMA_F16(af[mf], bf[nt], acc[mf][nt]);
    }
    #pragma unroll
    for (int mf = 0; mf < 4; mf++)
      #pragma unroll
      for (int r = 0; r < 4; r++) {
        int rr = mf * 16 + quad * 4 + r;
        int row = row0 + rr;
        int bb = row >> 12, p = row & 4095, hh = p >> 6, ww = p & 63;
        int m = (hh & 7) * 8 + (ww & 7), n = (hh >> 3) * 8 + (ww >> 3);
        size_t zrow = ((size_t)((bb * 64 + m) * 64 + n)) * 256;
        size_t xrow = (size_t)row * 256;
        #pragma unroll
        for (int nt = 0; nt < 4; nt++) {
          int col = w * 64 + nt * 16 + l16;
          float vres = x[xrow + col] + (float)Z0[zrow + col] + (float)Z1[zrow + col];
          float vv = acc[mf][nt][r] + b2[col];
          out[xrow + col] = vv + vres;
        }
      }
  }
}

extern "C" void kernel_launch(void* const* d_in, const int* in_sizes, int n_in,
                              void* d_out, int out_size, void* d_ws, size_t ws_size,
                              hipStream_t stream) {
  (void)in_sizes; (void)n_in; (void)out_size; (void)ws_size;
  const float* x    = (const float*)d_in[0];
  const float* ln1w = (const float*)d_in[1];
  const float* ln1b = (const float*)d_in[2];
  const float* q    = (const float*)d_in[3];
  const float* k    = (const float*)d_in[4];
  const float* v    = (const float*)d_in[5];
  const float* o    = (const float*)d_in[6];
  const float* ln2w = (const float*)d_in[7];
  const float* ln2b = (const float*)d_in[8];
  const float* w1   = (const float*)d_in[9];
  const float* b1   = (const float*)d_in[10];
  const float* w2   = (const float*)d_in[11];
  const float* b2   = (const float*)d_in[12];
  float* out = (float*)d_out;

  const size_t ROWS = (size_t)Bc * Tc;        // 32768
  const size_t ELTS = ROWS * Dc;              // 8,388,608
  const size_t MB16 = ELTS * sizeof(half_t);  // 16 MiB
  char* ws = (char*)d_ws;
  float*  osumB = (float*)ws;
  half_t* Mt    = (half_t*)(ws + (64 << 10));
  half_t* vt    = (half_t*)(ws + (64 << 10) + (1 << 20));
  half_t* w1t   = (half_t*)(ws + (64 << 10) + (1 << 20) + (128 << 10));
  half_t* w2t   = (half_t*)(ws + (64 << 10) + (1 << 20) + (256 << 10));
  half_t* aH    = (half_t*)(ws + (2 << 20));
  half_t* Zb0   = (half_t*)(ws + (2 << 20) + MB16);
  half_t* Zb1   = (half_t*)(ws + (2 << 20) + 2 * MB16);

  // merged prep: prepM (512) | prepT (768) | osum (8) | ln1 (512 x 64 rows)
  prep_kernel <<<1800, 256, 0, stream>>>(q, k, v, w1, w2, o, x, ln1w, ln1b,
                                         Mt, vt, w1t, w2t, osumB, aH);
  // fused attention: ONE 1024-block dispatch (mode 0 -> Z0, mode 1 -> Z1)
  attn_kernel <<<1024, 256, 0, stream>>>(aH, Mt, vt, osumB, Zb0, Zb1);
  // fused tail: resid + LN2 + fc1 + fc2 + resid -> out (512 x 64-row blocks, one round)
  mlp_kernel  <<<ROWS / 64, 256, 0, stream>>>(x, Zb0, Zb1, ln2w, ln2b, w1t, b1, w2t, b2, out);
}